// Round 6
// baseline (250.853 us; speedup 1.0000x reference)
//
#include <hip/hip_runtime.h>

// LIF recurrence, T=4, TAU=1.0, THRESH=1.0.
// mem = mem + x[t]; spike = (mem - 1 > 0); mem = spike ? 0 : mem.
//
// v5: v4 + __launch_bounds__(256, 4). v4's VGPR_Count=36 proved the load
// batch was SPILLED TO SCRATCH (64 live data VGPRs at the sched_barrier are
// impossible in 36 regs) -> 105us regression from scratch traffic. The
// default occupancy heuristic capped VGPRs near 40; min_waves=4/EU raises
// the cap to 128 VGPRs so the 16-load batch (T=4 x CHUNKS=4 f32x4) can
// materialize in registers. 16KB in flight/wave x 16 waves/CU = 256KB/CU.
// This is the decisive test of the congested-latency/MLP theory; VGPR_Count
// in the counters is the built-in check that the pipeline materialized.
// NT stores kept (proven no-RFO: FETCH=65MB).

#define LIF_T 4
#define CHUNKS 4

typedef float f32x4 __attribute__((ext_vector_type(4)));

__device__ __forceinline__ f32x4 lif_step(f32x4& mem, f32x4 xt) {
    mem.x += xt.x;
    mem.y += xt.y;
    mem.z += xt.z;
    mem.w += xt.w;
    f32x4 sp;
    sp.x = (mem.x > 1.0f) ? 1.0f : 0.0f;
    sp.y = (mem.y > 1.0f) ? 1.0f : 0.0f;
    sp.z = (mem.z > 1.0f) ? 1.0f : 0.0f;
    sp.w = (mem.w > 1.0f) ? 1.0f : 0.0f;
    mem.x = (sp.x > 0.f) ? 0.f : mem.x;
    mem.y = (sp.y > 0.f) ? 0.f : mem.y;
    mem.z = (sp.z > 0.f) ? 0.f : mem.z;
    mem.w = (sp.w > 0.f) ? 0.f : mem.w;
    return sp;
}

__global__ __launch_bounds__(256, 4) void
lif_spike_kernel(const float* __restrict__ x, float* __restrict__ out,
                 int n_vec, int stride /* = total threads */) {
    const int tid0 = blockIdx.x * blockDim.x + threadIdx.x;
    const f32x4* __restrict__ xv = reinterpret_cast<const f32x4*>(x);
    f32x4* __restrict__ ov = reinterpret_cast<f32x4*>(out);

    if (tid0 + (CHUNKS - 1) * stride < n_vec) {
        // ---- fast path (whole grid in the exact bench shape) ----
        // Issue all 16 independent loads back-to-back; 64 data VGPRs live.
        f32x4 v[LIF_T][CHUNKS];
#pragma unroll
        for (int t = 0; t < LIF_T; ++t)
#pragma unroll
            for (int c = 0; c < CHUNKS; ++c)
                v[t][c] = xv[(size_t)t * n_vec + tid0 + (size_t)c * stride];

        // Pin the schedule: loads may not sink below this point.
        __builtin_amdgcn_sched_barrier(0);

        f32x4 mem[CHUNKS];
#pragma unroll
        for (int c = 0; c < CHUNKS; ++c) mem[c] = (f32x4){0.f, 0.f, 0.f, 0.f};

#pragma unroll
        for (int t = 0; t < LIF_T; ++t) {
#pragma unroll
            for (int c = 0; c < CHUNKS; ++c) {
                f32x4 sp = lif_step(mem[c], v[t][c]);
                __builtin_nontemporal_store(
                    sp, &ov[(size_t)t * n_vec + tid0 + (size_t)c * stride]);
            }
        }
    } else {
        // ---- tail path (never taken in the exact bench shape) ----
#pragma unroll
        for (int c = 0; c < CHUNKS; ++c) {
            int idx = tid0 + c * stride;
            if (idx >= n_vec) break;  // idx monotone in c
            f32x4 memc = (f32x4){0.f, 0.f, 0.f, 0.f};
#pragma unroll
            for (int t = 0; t < LIF_T; ++t) {
                f32x4 xt = xv[(size_t)t * n_vec + idx];
                f32x4 sp = lif_step(memc, xt);
                __builtin_nontemporal_store(sp, &ov[(size_t)t * n_vec + idx]);
            }
        }
    }
}

extern "C" void kernel_launch(void* const* d_in, const int* in_sizes, int n_in,
                              void* d_out, int out_size, void* d_ws, size_t ws_size,
                              hipStream_t stream) {
    const float* x = (const float*)d_in[0];
    float* out = (float*)d_out;

    int n = out_size / LIF_T;      // elements per timestep (8,388,608)
    int n_vec = n / 4;             // float4 groups per timestep (2,097,152)

    const int block = 256;
    int grid = (n_vec + block * CHUNKS - 1) / (block * CHUNKS);  // 2048
    int stride = grid * block;                                   // 524,288
    lif_spike_kernel<<<grid, block, 0, stream>>>(x, out, n_vec, stride);
}

// Round 12
// 227.329 us; speedup vs baseline: 1.1035x; 1.1035x over previous
//
#include <hip/hip_runtime.h>

// LIF recurrence, T=4, TAU=1.0, THRESH=1.0.
// mem = mem + x[t]; spike = (mem - 1 > 0); mem = spike ? 0 : mem.
//
// v6 (6th submit — rounds 7-11 were broker timeouts, kernel never ran):
// two-in-one probe of the surviving hypotheses.
// (a) DRAM window locality: block owns 16KB-contiguous chunks per plane
//     (vs v3-v5's 8MB-strided scatter).
// (b) CHEAP 4-deep MLP: the 4 chunk loads share ONE base address with
//     c*4096B offsets -> one addr reg + imm offsets, batch fits in ~32
//     VGPRs. v3-v5 failed to materialize MLP because their 8MB strides
//     needed per-load 64b address math (~80 VGPRs -> allocator spilled,
//     VGPR_Count stuck at 36). No sched_barrier / no launch-bounds min.
// Signals: VGPR_Count ~32-40 => batch materialized; dur 82->50-65 if MLP
// or locality was the limiter; null => declare structural ceiling
// (~265MB real traffic, FETCH_SIZE 2x-undercount per gfx94x formula).
// NT stores kept (proven no-RFO, time-neutral vs regular).

#define LIF_T 4
#define CHUNKS 4

typedef float f32x4 __attribute__((ext_vector_type(4)));

__device__ __forceinline__ f32x4 lif_step(f32x4& mem, f32x4 xt) {
    mem.x += xt.x;
    mem.y += xt.y;
    mem.z += xt.z;
    mem.w += xt.w;
    f32x4 sp;
    sp.x = (mem.x > 1.0f) ? 1.0f : 0.0f;
    sp.y = (mem.y > 1.0f) ? 1.0f : 0.0f;
    sp.z = (mem.z > 1.0f) ? 1.0f : 0.0f;
    sp.w = (mem.w > 1.0f) ? 1.0f : 0.0f;
    mem.x = (sp.x > 0.f) ? 0.f : mem.x;
    mem.y = (sp.y > 0.f) ? 0.f : mem.y;
    mem.z = (sp.z > 0.f) ? 0.f : mem.z;
    mem.w = (sp.w > 0.f) ? 0.f : mem.w;
    return sp;
}

__global__ __launch_bounds__(256) void
lif_spike_kernel(const float* __restrict__ x, float* __restrict__ out, int n_vec) {
    // Block b owns float4 indices [b*1024, b*1024+1024) of every plane:
    // 4 contiguous 16KB streams (one per timestep), 4 loads per wave in
    // flight at immediate-offset cost.
    const int base = blockIdx.x * (256 * CHUNKS) + threadIdx.x;
    const f32x4* __restrict__ xv = reinterpret_cast<const f32x4*>(x);
    f32x4* __restrict__ ov = reinterpret_cast<f32x4*>(out);

    if (base + (CHUNKS - 1) * 256 < n_vec) {
        // ---- fast path (exact cover in the bench shape: 2048*1024 == n_vec) ----
        f32x4 mem[CHUNKS];
#pragma unroll
        for (int c = 0; c < CHUNKS; ++c) mem[c] = (f32x4){0.f, 0.f, 0.f, 0.f};

#pragma unroll
        for (int t = 0; t < LIF_T; ++t) {
            const size_t p = (size_t)t * n_vec + base;
            f32x4 xt[CHUNKS];
            // 4 independent loads off one base, 4KB apart
#pragma unroll
            for (int c = 0; c < CHUNKS; ++c) xt[c] = xv[p + c * 256];
#pragma unroll
            for (int c = 0; c < CHUNKS; ++c) {
                f32x4 sp = lif_step(mem[c], xt[c]);
                __builtin_nontemporal_store(sp, &ov[p + c * 256]);
            }
        }
    } else {
        // ---- tail path (not taken in the exact bench shape) ----
        f32x4 memc[CHUNKS];
#pragma unroll
        for (int c = 0; c < CHUNKS; ++c) memc[c] = (f32x4){0.f, 0.f, 0.f, 0.f};
#pragma unroll
        for (int t = 0; t < LIF_T; ++t) {
#pragma unroll
            for (int c = 0; c < CHUNKS; ++c) {
                int idx = base + c * 256;
                if (idx < n_vec) {
                    f32x4 sp = lif_step(memc[c], xv[(size_t)t * n_vec + idx]);
                    __builtin_nontemporal_store(sp, &ov[(size_t)t * n_vec + idx]);
                }
            }
        }
    }
}

extern "C" void kernel_launch(void* const* d_in, const int* in_sizes, int n_in,
                              void* d_out, int out_size, void* d_ws, size_t ws_size,
                              hipStream_t stream) {
    const float* x = (const float*)d_in[0];
    float* out = (float*)d_out;

    int n = out_size / LIF_T;      // elements per timestep (8,388,608)
    int n_vec = n / 4;             // float4 groups per timestep (2,097,152)

    const int block = 256;
    int grid = (n_vec + block * CHUNKS - 1) / (block * CHUNKS);  // 2048
    lif_spike_kernel<<<grid, block, 0, stream>>>(x, out, n_vec);
}